// Round 12
// baseline (1348.578 us; speedup 1.0000x reference)
//
#include <hip/hip_runtime.h>

typedef unsigned short ushort_t;
typedef unsigned int   uint_t;

#define NTOK 50176          // B*D*Hp*Wp = 2*8*56*56
#define NWIN 98             // (8/4)*(56/8)*(56/8)
#define NBIAS 1575          // 7*15*15

typedef __attribute__((ext_vector_type(8))) short bf16x8;
typedef __attribute__((ext_vector_type(4))) float floatx4;
typedef __attribute__((ext_vector_type(4))) ushort_t ushortx4;

static __device__ __forceinline__ ushort_t f2b(float f) {
    union { float f; uint_t u; } v; v.f = f;
    uint_t u = v.u + 0x7fffu + ((v.u >> 16) & 1u);
    return (ushort_t)(u >> 16);
}

// ---------------- weight transpose + fp32->bf16 cast: dst[n*K+k] = bf16(src[k*N+n])
__global__ void transpose_w(const float* __restrict__ src, ushort_t* __restrict__ dst,
                            int K, int N) {
    long base = (long)blockIdx.y * K * N;
    int idx = blockIdx.x * 256 + threadIdx.x;
    if (idx < K * N) {
        int k = idx / N, n = idx - k * N;
        dst[base + (long)n * K + k] = f2b(src[base + idx]);
    }
}

// ---------------- elementwise fp32 -> bf16 cast
__global__ void cast_bf16(const float* __restrict__ src, ushort_t* __restrict__ dst, int n) {
    int i = blockIdx.x * 256 + threadIdx.x;
    if (i < n) dst[i] = f2b(src[i]);
}

// ---------------- fused bias+mask table generation
// Btab layout PER (slot,head): T[i>>2][j][i&3] fp32 (so the 4 row-values a lane
// needs are one float4), value = (bias + mask) * log2(e)
// slots: L0: c0 @0 ; L1: c0..7 @1..8 ; L2: c0 @9 ; L3: c0..7 @10..17
// class bits: (cd<<2)|(ch<<1)|cw  where cd=(wd==1), ch=(wh==6), cw=(ww==6)
__global__ void gen_btab(const float* __restrict__ bias_tab, float* __restrict__ Btab) {
    int slot = blockIdx.y;
    int layer, cls;
    if (slot == 0)      { layer = 0; cls = 0; }
    else if (slot < 9)  { layer = 1; cls = slot - 1; }
    else if (slot == 9) { layer = 2; cls = 0; }
    else                { layer = 3; cls = slot - 10; }
    int idx = blockIdx.x * 256 + threadIdx.x;    // 8 heads * 65536
    int hd = idx >> 16;
    int ij = idx & 65535;
    int i = ij >> 8, j = ij & 255;
    int di = i >> 6, hi = (i >> 3) & 7, wi = i & 7;
    int dj = j >> 6, hj = (j >> 3) & 7, wj = j & 7;
    int rel = (di - dj + 3) * 225 + (hi - hj + 7) * 15 + (wi - wj + 7);
    float v = bias_tab[((long)layer * NBIAS + rel) * 8 + hd];
    int cd = cls >> 2, ch = (cls >> 1) & 1, cw = cls & 1;
    int ri = (cd ? (di < 2 ? 1 : 2) : 0) * 9 + (ch ? (hi < 4 ? 1 : 2) : 0) * 3 + (cw ? (wi < 4 ? 1 : 2) : 0);
    int rj = (cd ? (dj < 2 ? 1 : 2) : 0) * 9 + (ch ? (hj < 4 ? 1 : 2) : 0) * 3 + (cw ? (wj < 4 ? 1 : 2) : 0);
    if (ri != rj) v = -1e9f;
    long off = (long)slot * 524288 + (long)hd * 65536 + ((i >> 2) * 1024 + j * 4 + (i & 3));
    Btab[off] = v * 1.4426950408889634f;
}

// ---------------- im2row: A[tok, 64] bf16 patch matrix from X (NCDHW fp32)
__global__ void im2row(const float* __restrict__ X, ushort_t* __restrict__ A) {
    int idx = blockIdx.x * 256 + threadIdx.x;   // NTOK*16 total
    int t = idx >> 4;
    int k = idx & 15;
    int ic = k >> 2, kh = k & 3;
    int w = t % 56, h = (t / 56) % 56, d = (t / 3136) % 8, b = t / 25088;
    long xi = (((long)(b * 4 + ic) * 8 + d) * 224 + (h * 4 + kh)) * 224 + w * 4;
    float4 u = *(const float4*)(X + xi);
    ushort_t* ap = A + (long)t * 64 + ic * 16 + kh * 4;
    ap[0] = f2b(u.x); ap[1] = f2b(u.y); ap[2] = f2b(u.z); ap[3] = f2b(u.w);
}

// ---------------- LayerNorm: 4 tokens per block, one wave per token; fp32 in, bf16 out
// float4 loads (16B/lane), ushort4 stores (8B/lane)
__global__ void ln_kernel(const float* __restrict__ Y, ushort_t* __restrict__ Xn,
                          const float* __restrict__ S, const float* __restrict__ Bb) {
    int wv = threadIdx.x >> 6, lane = threadIdx.x & 63;
    long t = (long)blockIdx.x * 4 + wv;
    float4 u = *(const float4*)(Y + t * 256 + lane * 4);
    float s = u.x + u.y + u.z + u.w;
    float s2 = u.x * u.x + u.y * u.y + u.z * u.z + u.w * u.w;
#pragma unroll
    for (int off = 32; off; off >>= 1) { s += __shfl_xor(s, off, 64); s2 += __shfl_xor(s2, off, 64); }
    float mu = s * (1.f / 256.f);
    float var = s2 * (1.f / 256.f) - mu * mu;
    float rstd = rsqrtf(var + 1e-5f);
    float4 sc = *(const float4*)(S + lane * 4);
    float4 bb = *(const float4*)(Bb + lane * 4);
    ushortx4 o;
    o.x = f2b((u.x - mu) * rstd * sc.x + bb.x);
    o.y = f2b((u.y - mu) * rstd * sc.y + bb.y);
    o.z = f2b((u.z - mu) * rstd * sc.z + bb.z);
    o.w = f2b((u.w - mu) * rstd * sc.w + bb.w);
    *(ushortx4*)(Xn + t * 256 + lane * 4) = o;
}

// ---------------- GEMM: C[M,N] = A[M,K] @ B[K,N] via BT[N,K]; 128x128 tile,
// double-buffered LDS, 2-phase: stage(t+1) issued before compute(t), ONE barrier/iter.
// 1D grid (nm*ny blocks) with XCD-chunked swizzle: xcd = bid&7 owns m-tiles
// [xcd*nm/8, ...), covering all n-tiles of each m-tile consecutively -> A-panel
// fetched once per XCD into L2 and reused ny times.
// launch_bounds(256,2): min-2 (NOT 3 — VGPR cap at 3 regressed, round 11).
// mode 0: store bf16; mode 1: bias+gelu bf16; mode 2: Y += acc+bias (fp32); mode 3: Y = acc+bias (fp32)
__global__ __launch_bounds__(256, 2) void gemm_bt(
    const ushort_t* __restrict__ A, const ushort_t* __restrict__ BT,
    int M, int N, int K,
    const float* __restrict__ bias, int mode,
    ushort_t* __restrict__ C, float* __restrict__ Y) {
    __shared__ ushort_t As[2][128 * 32];
    __shared__ ushort_t Bs[2][128 * 32];
    const int tid = threadIdx.x;
    const int wv = tid >> 6;
    const int lane = tid & 63;
    const int quad = lane >> 4;
    const int l15 = lane & 15;
    const int ny = N >> 7;
    const int nm = gridDim.x / ny;          // 392, divisible by 8
    const int per = nm >> 3;                // m-tiles per XCD
    const int xcd = blockIdx.x & 7;
    const int idx = blockIdx.x >> 3;
    const int mseq = idx / ny;
    const int nt = idx - mseq * ny;
    const long m0 = (long)(xcd * per + mseq) * 128;
    const long n0 = (long)nt * 128;
    const int wm = (wv & 1) * 64;
    const int wn = (wv >> 1) * 64;
    const int r_loc = lane >> 2;
    const int k_loc = (lane & 3) * 8;

    floatx4 acc[4][4] = {};

    const ushort_t* Ab = A + m0 * K;
    const ushort_t* Bb = BT + n0 * K;
    const int slot = wv * 2;
    const int row0 = slot * 16 + r_loc;
    const int nkt = K >> 5;

    // prologue: stage tile 0 into buf 0
#pragma unroll
    for (int q = 0; q < 2; ++q) {
        __builtin_amdgcn_global_load_lds(
            (const __attribute__((address_space(1))) void*)(Ab + (long)(row0 + q * 16) * K + k_loc),
            (__attribute__((address_space(3))) void*)(&As[0][(slot + q) * 512]), 16, 0, 0);
        __builtin_amdgcn_global_load_lds(
            (const __attribute__((address_space(1))) void*)(Bb + (long)(row0 + q * 16) * K + k_loc),
            (__attribute__((address_space(3))) void*)(&Bs[0][(slot + q) * 512]), 16, 0, 0);
    }
    __syncthreads();

    int cur = 0;
    for (int t = 0; t < nkt; ++t) {
        if (t + 1 < nkt) {
            const int kt = (t + 1) << 5;
#pragma unroll
            for (int q = 0; q < 2; ++q) {
                __builtin_amdgcn_global_load_lds(
                    (const __attribute__((address_space(1))) void*)(Ab + (long)(row0 + q * 16) * K + kt + k_loc),
                    (__attribute__((address_space(3))) void*)(&As[cur ^ 1][(slot + q) * 512]), 16, 0, 0);
                __builtin_amdgcn_global_load_lds(
                    (const __attribute__((address_space(1))) void*)(Bb + (long)(row0 + q * 16) * K + kt + k_loc),
                    (__attribute__((address_space(3))) void*)(&Bs[cur ^ 1][(slot + q) * 512]), 16, 0, 0);
            }
        }
        bf16x8 af[4], bfr[4];
#pragma unroll
        for (int i = 0; i < 4; ++i) {
            af[i]  = *(const bf16x8*)(&As[cur][(wm + i * 16 + l15) * 32 + quad * 8]);
            bfr[i] = *(const bf16x8*)(&Bs[cur][(wn + i * 16 + l15) * 32 + quad * 8]);
        }
#pragma unroll
        for (int mi = 0; mi < 4; ++mi)
#pragma unroll
            for (int ni = 0; ni < 4; ++ni)
                acc[mi][ni] = __builtin_amdgcn_mfma_f32_16x16x32_bf16(af[mi], bfr[ni], acc[mi][ni], 0, 0, 0);
        __syncthreads();
        cur ^= 1;
    }

    if (mode == 2) {
#pragma unroll
        for (int mi = 0; mi < 4; ++mi)
#pragma unroll
            for (int ni = 0; ni < 4; ++ni) {
                long col = n0 + wn + ni * 16 + l15;
                float bv = bias[col];
#pragma unroll
                for (int r = 0; r < 4; ++r) {
                    long row = m0 + wm + mi * 16 + quad * 4 + r;
                    Y[row * N + col] += acc[mi][ni][r] + bv;
                }
            }
    } else if (mode == 3) {
#pragma unroll
        for (int mi = 0; mi < 4; ++mi)
#pragma unroll
            for (int ni = 0; ni < 4; ++ni) {
                long col = n0 + wn + ni * 16 + l15;
                float bv = bias[col];
#pragma unroll
                for (int r = 0; r < 4; ++r) {
                    long row = m0 + wm + mi * 16 + quad * 4 + r;
                    Y[row * N + col] = acc[mi][ni][r] + bv;
                }
            }
    } else {
#pragma unroll
        for (int mi = 0; mi < 4; ++mi)
#pragma unroll
            for (int ni = 0; ni < 4; ++ni) {
                long col = n0 + wn + ni * 16 + l15;
                float bv = bias ? bias[col] : 0.f;
#pragma unroll
                for (int r = 0; r < 4; ++r) {
                    long row = m0 + wm + mi * 16 + quad * 4 + r;
                    float v = acc[mi][ni][r] + bv;
                    if (mode == 1) {
                        // gelu(v) = v * sigmoid(2u), u = 0.79788456*(v + 0.044715 v^3)
                        float u = 0.7978845608028654f * (v + 0.044715f * v * v * v);
                        float e = __builtin_amdgcn_exp2f(-2.8853900817779268f * u);
                        v = v * __builtin_amdgcn_rcpf(1.f + e);
                    }
                    C[row * N + col] = f2b(v);
                }
            }
    }
}

// ---------------- MFMA window attention: 1D grid, 8 waves, 2 row-groups/wave.
// Bijective XCD swizzle: 1568 blocks = 8 XCDs x 196; orig = (bid%8)*196 + bid/8
// gives each XCD one head's 196 (win,batch) blocks -> its 256KB bias table slice
// stays L2-resident. Bias table in T[i/4][j][i%4] layout -> one float4 per lane
// covers r=0..3 (16 coalesced loads/rg instead of 64 scalars).
#define PSTR 134            // 67 dwords, odd mod 32
#define VTSTR 266           // 133 dwords, odd mod 32
__global__ __launch_bounds__(512, 4) void attn_mfma(
    const ushort_t* __restrict__ QKV, ushort_t* __restrict__ O,
    const float* __restrict__ Btab, int shifted) {
    __shared__ ushort_t Ks[256 * 32];                 // K rows [tok][dim]   16384 B
    __shared__ ushort_t Vt[32 * VTSTR];               // V^T [dim][tok]      17024 B
    __shared__ ushort_t Pl[8 * 16 * PSTR];            // per-wave P (128 col) 34304 B
    __shared__ int tok_s[256];                        //                      1024 B

    const int tid = threadIdx.x;
    const int wv = tid >> 6;
    const int lane = tid & 63;
    const int quad = lane >> 4;
    const int l15 = lane & 15;
    const int bid = blockIdx.x;
    const int orig = (bid & 7) * 196 + (bid >> 3);
    const int hd = orig / 196;
    const int rem = orig - hd * 196;
    const int b = rem / 98;
    const int wdx = rem - b * 98;
    const int wd = wdx / 49;
    const int wh = (wdx / 7) % 7;
    const int ww = wdx % 7;

    const int cls = shifted ? ((wd << 2) | ((wh == 6) << 1) | (ww == 6)) : 0;
    const float* bt = Btab + ((long)(cls * 8 + hd)) * 65536;

    if (tid < 256) {
        const int t = tid;
        const int di = t >> 6, hi = (t >> 3) & 7, wi = t & 7;
        const int d = wd * 4 + di, h = wh * 8 + hi, w = ww * 8 + wi;
        int d0 = d, h0 = h, w0 = w;
        if (shifted) { d0 = (d + 2) & 7; h0 = (h + 4) % 56; w0 = (w + 4) % 56; }
        const long tok = ((long)((b * 8 + d0) * 56 + h0)) * 56 + w0;
        tok_s[t] = (int)tok;
        const uint4* kp = (const uint4*)(QKV + tok * 768 + 256 + hd * 32);
        const uint4* vp = (const uint4*)(QKV + tok * 768 + 512 + hd * 32);
        uint4* kd = (uint4*)(Ks + t * 32);
#pragma unroll
        for (int p = 0; p < 4; ++p) kd[p] = kp[p];
#pragma unroll
        for (int p = 0; p < 4; ++p) {
            uint4 vvu = vp[p];
            uint_t uu[4] = {vvu.x, vvu.y, vvu.z, vvu.w};
#pragma unroll
            for (int e = 0; e < 4; ++e) {
                int dd = p * 8 + e * 2;
                Vt[dd * VTSTR + t]       = (ushort_t)(uu[e] & 0xffffu);
                Vt[(dd + 1) * VTSTR + t] = (ushort_t)(uu[e] >> 16);
            }
        }
    }
    __syncthreads();

    const float scale = 0.17677669529663687f * 1.4426950408889634f;  // 1/sqrt(32) * log2(e)
    ushort_t* Pw = Pl + wv * 16 * PSTR;

    for (int rg = 0; rg < 2; ++rg) {
        const int rti = wv * 2 + rg;
        bf16x8 aq;
        {
            int tq = tok_s[rti * 16 + l15];
            const uint4* qp = (const uint4*)(QKV + (long)tq * 768 + hd * 32 + quad * 8);
            union { uint4 u; bf16x8 v; } cv; cv.u = *qp; aq = cv.v;
        }
        // bias base: rows rti*16+quad*4.., col l15; layout T[i/4][j][i%4]
        const float* bp = bt + (long)(rti * 4 + quad) * 1024 + l15 * 4;
        floatx4 Sc[16];
        float m4[4] = {-3e38f, -3e38f, -3e38f, -3e38f};
#pragma unroll
        for (int hf = 0; hf < 2; ++hf) {
            floatx4 bb4[8];
#pragma unroll
            for (int n8 = 0; n8 < 8; ++n8)
                bb4[n8] = *(const floatx4*)(bp + (hf * 8 + n8) * 64);   // 16B coalesced
#pragma unroll
            for (int n8 = 0; n8 < 8; ++n8) {
                const int nt = hf * 8 + n8;
                bf16x8 bk = *(const bf16x8*)(Ks + (nt * 16 + l15) * 32 + quad * 8);
                floatx4 z = {};
                Sc[nt] = __builtin_amdgcn_mfma_f32_16x16x32_bf16(aq, bk, z, 0, 0, 0);
            }
#pragma unroll
            for (int n8 = 0; n8 < 8; ++n8) {
                const int nt = hf * 8 + n8;
#pragma unroll
                for (int r = 0; r < 4; ++r) {
                    float s = fmaf(Sc[nt][r], scale, bb4[n8][r]);   // bias+mask, log2 domain
                    Sc[nt][r] = s;
                    m4[r] = fmaxf(m4[r], s);
                }
            }
        }
#pragma unroll
        for (int r = 0; r < 4; ++r) {
            m4[r] = fmaxf(m4[r], __shfl_xor(m4[r], 1));
            m4[r] = fmaxf(m4[r], __shfl_xor(m4[r], 2));
            m4[r] = fmaxf(m4[r], __shfl_xor(m4[r], 4));
            m4[r] = fmaxf(m4[r], __shfl_xor(m4[r], 8));
        }
        float l4[4] = {0.f, 0.f, 0.f, 0.f};
#pragma unroll
        for (int nt = 0; nt < 16; ++nt)
#pragma unroll
            for (int r = 0; r < 4; ++r) {
                float p = __builtin_amdgcn_exp2f(Sc[nt][r] - m4[r]);
                l4[r] += p;
                Sc[nt][r] = p;
            }
#pragma unroll
        for (int r = 0; r < 4; ++r) {
            l4[r] += __shfl_xor(l4[r], 1);
            l4[r] += __shfl_xor(l4[r], 2);
            l4[r] += __shfl_xor(l4[r], 4);
            l4[r] += __shfl_xor(l4[r], 8);
        }
        float inv4[4];
#pragma unroll
        for (int r = 0; r < 4; ++r) inv4[r] = 1.f / l4[r];

        floatx4 oa[2] = {};
#pragma unroll
        for (int hf = 0; hf < 2; ++hf) {
#pragma unroll
            for (int n8 = 0; n8 < 8; ++n8)
#pragma unroll
                for (int r = 0; r < 4; ++r)
                    Pw[(quad * 4 + r) * PSTR + n8 * 16 + l15] = f2b(Sc[hf * 8 + n8][r]);
            __builtin_amdgcn_s_waitcnt(0xC07F);       // lgkmcnt(0)
            __builtin_amdgcn_wave_barrier();
#pragma unroll
            for (int ct = 0; ct < 2; ++ct)
#pragma unroll
                for (int kt = 0; kt < 4; ++kt) {
                    bf16x8 ap = *(const bf16x8*)(Pw + l15 * PSTR + kt * 32 + quad * 8);
                    bf16x8 bv = *(const bf16x8*)(Vt + (ct * 16 + l15) * VTSTR + hf * 128 + kt * 32 + quad * 8);
                    oa[ct] = __builtin_amdgcn_mfma_f32_16x16x32_bf16(ap, bv, oa[ct], 0, 0, 0);
                }
            __builtin_amdgcn_s_waitcnt(0xC07F);
            __builtin_amdgcn_wave_barrier();
        }
#pragma unroll
        for (int ct = 0; ct < 2; ++ct)
#pragma unroll
            for (int r = 0; r < 4; ++r) {
                int i = rti * 16 + quad * 4 + r;
                long tq = tok_s[i];
                O[tq * 256 + hd * 32 + ct * 16 + l15] = f2b(oa[ct][r] * inv4[r]);
            }
    }
}

// ---------------- final permute: y (tok, C) fp32 -> out (B, C, D, Hp, Wp) fp32
__global__ void out_permute(const float* __restrict__ Y, float* __restrict__ Out) {
    __shared__ float tile[64][65];
    const int t0 = blockIdx.x * 64;
    const int c0 = blockIdx.y * 64;
    const int tid = threadIdx.x;
    const int a = tid >> 6;
    const int bx = tid & 63;
#pragma unroll
    for (int s8 = 0; s8 < 16; ++s8) {
        int tt = a + s8 * 4;
        tile[tt][bx] = Y[(long)(t0 + tt) * 256 + c0 + bx];
    }
    __syncthreads();
#pragma unroll
    for (int s8 = 0; s8 < 16; ++s8) {
        int cc = a + s8 * 4;
        int tok = t0 + bx;
        int bb = tok / 25088;
        int rem = tok - bb * 25088;
        Out[((long)(bb * 256 + c0 + cc)) * 25088 + rem] = tile[bx][cc];
    }
}

extern "C" void kernel_launch(void* const* d_in, const int* in_sizes, int n_in,
                              void* d_out, int out_size, void* d_ws, size_t ws_size,
                              hipStream_t stream) {
    (void)in_sizes; (void)n_in; (void)out_size; (void)ws_size;
    const float* x        = (const float*)d_in[0];
    const float* conv_w   = (const float*)d_in[1];
    const float* conv_b   = (const float*)d_in[2];
    const float* ln1_s    = (const float*)d_in[3];
    const float* ln1_b    = (const float*)d_in[4];
    const float* qkv_w    = (const float*)d_in[5];
    const float* out_w    = (const float*)d_in[6];
    const float* out_b    = (const float*)d_in[7];
    const float* bias_tab = (const float*)d_in[8];
    const float* ln2_s    = (const float*)d_in[9];
    const float* ln2_b    = (const float*)d_in[10];
    const float* fc1_w    = (const float*)d_in[11];
    const float* fc1_b    = (const float*)d_in[12];
    const float* fc2_w    = (const float*)d_in[13];
    const float* fc2_b    = (const float*)d_in[14];
    float* out = (float*)d_out;

    char* ws = (char*)d_ws;
    float*    y    = (float*)ws;    ws += (size_t)NTOK * 256 * 4;   // fp32 residual stream
    ushort_t* big  = (ushort_t*)ws; ws += (size_t)NTOK * 1024 * 2;  // qkv/h1/im2row bf16
    ushort_t* xob  = (ushort_t*)ws; ws += (size_t)NTOK * 256 * 2;   // LN out / attn out bf16
    ushort_t* bt_qkv = (ushort_t*)ws; ws += (size_t)4 * 768 * 256 * 2;
    ushort_t* bt_out = (ushort_t*)ws; ws += (size_t)4 * 256 * 256 * 2;
    ushort_t* bt_fc1 = (ushort_t*)ws; ws += (size_t)4 * 1024 * 256 * 2;
    ushort_t* bt_fc2 = (ushort_t*)ws; ws += (size_t)4 * 256 * 1024 * 2;
    ushort_t* cw_bf  = (ushort_t*)ws; ws += (size_t)256 * 64 * 2;
    float*    btab   = (float*)ws;  ws += (size_t)18 * 524288 * 4;  // fused bias+mask tables

    transpose_w<<<dim3((256 * 768 + 255) / 256, 4), 256, 0, stream>>>(qkv_w, bt_qkv, 256, 768);
    transpose_w<<<dim3((256 * 256 + 255) / 256, 4), 256, 0, stream>>>(out_w, bt_out, 256, 256);
    transpose_w<<<dim3((256 * 1024 + 255) / 256, 4), 256, 0, stream>>>(fc1_w, bt_fc1, 256, 1024);
    transpose_w<<<dim3((1024 * 256 + 255) / 256, 4), 256, 0, stream>>>(fc2_w, bt_fc2, 1024, 256);
    gen_btab<<<dim3(2048, 18), 256, 0, stream>>>(bias_tab, btab);

    // conv as GEMM: conv_w (O,I,1,4,4) is already BT[256][64] row-major — cast only
    cast_bf16<<<(256 * 64 + 255) / 256, 256, 0, stream>>>(conv_w, cw_bf, 256 * 64);
    im2row<<<NTOK * 16 / 256, 256, 0, stream>>>(x, big);
    gemm_bt<<<(NTOK / 128) * 2, 256, 0, stream>>>(
        big, cw_bf, NTOK, 256, 64, conv_b, 3, nullptr, y);

    static const int base_slot[4] = {0, 1, 9, 10};
    for (int i = 0; i < 4; ++i) {
        int sh = i & 1;
        ln_kernel<<<NTOK / 4, 256, 0, stream>>>(y, xob, ln1_s + i * 256, ln1_b + i * 256);
        gemm_bt<<<(NTOK / 128) * 6, 256, 0, stream>>>(
            xob, bt_qkv + (size_t)i * 768 * 256, NTOK, 768, 256, nullptr, 0, big, nullptr);
        attn_mfma<<<dim3(NWIN * 8 * 2), 512, 0, stream>>>(
            big, xob, btab + (size_t)base_slot[i] * 524288, sh);
        gemm_bt<<<(NTOK / 128) * 2, 256, 0, stream>>>(
            xob, bt_out + (size_t)i * 256 * 256, NTOK, 256, 256, out_b + i * 256, 2, nullptr, y);
        ln_kernel<<<NTOK / 4, 256, 0, stream>>>(y, xob, ln2_s + i * 256, ln2_b + i * 256);
        gemm_bt<<<(NTOK / 128) * 8, 256, 0, stream>>>(
            xob, bt_fc1 + (size_t)i * 1024 * 256, NTOK, 1024, 256, fc1_b + i * 1024, 1, big, nullptr);
        gemm_bt<<<(NTOK / 128) * 2, 256, 0, stream>>>(
            big, bt_fc2 + (size_t)i * 256 * 1024, NTOK, 256, 1024, fc2_b + i * 256, 2, nullptr, y);
    }

    out_permute<<<dim3(NTOK / 64, 4), 256, 0, stream>>>(y, out);
}

// Round 13
// 1306.028 us; speedup vs baseline: 1.0326x; 1.0326x over previous
//
#include <hip/hip_runtime.h>

typedef unsigned short ushort_t;
typedef unsigned int   uint_t;

#define NTOK 50176          // B*D*Hp*Wp = 2*8*56*56
#define NWIN 98             // (8/4)*(56/8)*(56/8)
#define NBIAS 1575          // 7*15*15

typedef __attribute__((ext_vector_type(8))) short bf16x8;
typedef __attribute__((ext_vector_type(4))) float floatx4;
typedef __attribute__((ext_vector_type(4))) ushort_t ushortx4;

static __device__ __forceinline__ ushort_t f2b(float f) {
    union { float f; uint_t u; } v; v.f = f;
    uint_t u = v.u + 0x7fffu + ((v.u >> 16) & 1u);
    return (ushort_t)(u >> 16);
}

// ---------------- weight transpose + fp32->bf16 cast: dst[n*K+k] = bf16(src[k*N+n])
__global__ void transpose_w(const float* __restrict__ src, ushort_t* __restrict__ dst,
                            int K, int N) {
    long base = (long)blockIdx.y * K * N;
    int idx = blockIdx.x * 256 + threadIdx.x;
    if (idx < K * N) {
        int k = idx / N, n = idx - k * N;
        dst[base + (long)n * K + k] = f2b(src[base + idx]);
    }
}

// ---------------- elementwise fp32 -> bf16 cast
__global__ void cast_bf16(const float* __restrict__ src, ushort_t* __restrict__ dst, int n) {
    int i = blockIdx.x * 256 + threadIdx.x;
    if (i < n) dst[i] = f2b(src[i]);
}

// ---------------- fused bias+mask table generation
// Btab layout PER (slot,head): T[i>>2][j][i&3] fp32 (so the 4 row-values a lane
// needs are one float4), value = (bias + mask) * log2(e).
// Thread index == OUTPUT offset (coalesced writes); (i,j) derived from it.
// slots: L0: c0 @0 ; L1: c0..7 @1..8 ; L2: c0 @9 ; L3: c0..7 @10..17
// class bits: (cd<<2)|(ch<<1)|cw  where cd=(wd==1), ch=(wh==6), cw=(ww==6)
__global__ void gen_btab(const float* __restrict__ bias_tab, float* __restrict__ Btab) {
    int slot = blockIdx.y;
    int layer, cls;
    if (slot == 0)      { layer = 0; cls = 0; }
    else if (slot < 9)  { layer = 1; cls = slot - 1; }
    else if (slot == 9) { layer = 2; cls = 0; }
    else                { layer = 3; cls = slot - 10; }
    int idx = blockIdx.x * 256 + threadIdx.x;    // 8 heads * 65536, == output offset
    int hd = idx >> 16;
    int off = idx & 65535;                       // (i>>2)*1024 + j*4 + (i&3)
    int i = ((off >> 10) << 2) | (off & 3);
    int j = (off >> 2) & 255;
    int di = i >> 6, hi = (i >> 3) & 7, wi = i & 7;
    int dj = j >> 6, hj = (j >> 3) & 7, wj = j & 7;
    int rel = (di - dj + 3) * 225 + (hi - hj + 7) * 15 + (wi - wj + 7);
    float v = bias_tab[((long)layer * NBIAS + rel) * 8 + hd];
    int cd = cls >> 2, ch = (cls >> 1) & 1, cw = cls & 1;
    int ri = (cd ? (di < 2 ? 1 : 2) : 0) * 9 + (ch ? (hi < 4 ? 1 : 2) : 0) * 3 + (cw ? (wi < 4 ? 1 : 2) : 0);
    int rj = (cd ? (dj < 2 ? 1 : 2) : 0) * 9 + (ch ? (hj < 4 ? 1 : 2) : 0) * 3 + (cw ? (wj < 4 ? 1 : 2) : 0);
    if (ri != rj) v = -1e9f;
    Btab[(long)slot * 524288 + idx] = v * 1.4426950408889634f;
}

// ---------------- im2row: A[tok, 64] bf16 patch matrix from X (NCDHW fp32)
__global__ void im2row(const float* __restrict__ X, ushort_t* __restrict__ A) {
    int idx = blockIdx.x * 256 + threadIdx.x;   // NTOK*16 total
    int t = idx >> 4;
    int k = idx & 15;
    int ic = k >> 2, kh = k & 3;
    int w = t % 56, h = (t / 56) % 56, d = (t / 3136) % 8, b = t / 25088;
    long xi = (((long)(b * 4 + ic) * 8 + d) * 224 + (h * 4 + kh)) * 224 + w * 4;
    float4 u = *(const float4*)(X + xi);
    ushort_t* ap = A + (long)t * 64 + ic * 16 + kh * 4;
    ap[0] = f2b(u.x); ap[1] = f2b(u.y); ap[2] = f2b(u.z); ap[3] = f2b(u.w);
}

// ---------------- LayerNorm: 4 tokens per block, one wave per token; fp32 in, bf16 out
// float4 loads (16B/lane), ushort4 stores (8B/lane)
__global__ void ln_kernel(const float* __restrict__ Y, ushort_t* __restrict__ Xn,
                          const float* __restrict__ S, const float* __restrict__ Bb) {
    int wv = threadIdx.x >> 6, lane = threadIdx.x & 63;
    long t = (long)blockIdx.x * 4 + wv;
    float4 u = *(const float4*)(Y + t * 256 + lane * 4);
    float s = u.x + u.y + u.z + u.w;
    float s2 = u.x * u.x + u.y * u.y + u.z * u.z + u.w * u.w;
#pragma unroll
    for (int off = 32; off; off >>= 1) { s += __shfl_xor(s, off, 64); s2 += __shfl_xor(s2, off, 64); }
    float mu = s * (1.f / 256.f);
    float var = s2 * (1.f / 256.f) - mu * mu;
    float rstd = rsqrtf(var + 1e-5f);
    float4 sc = *(const float4*)(S + lane * 4);
    float4 bb = *(const float4*)(Bb + lane * 4);
    ushortx4 o;
    o.x = f2b((u.x - mu) * rstd * sc.x + bb.x);
    o.y = f2b((u.y - mu) * rstd * sc.y + bb.y);
    o.z = f2b((u.z - mu) * rstd * sc.z + bb.z);
    o.w = f2b((u.w - mu) * rstd * sc.w + bb.w);
    *(ushortx4*)(Xn + t * 256 + lane * 4) = o;
}

// ---------------- GEMM: C[M,N] = A[M,K] @ B[K,N] via BT[N,K]; 128x128 tile,
// double-buffered LDS, 2-phase: stage(t+1) issued before compute(t), ONE barrier/iter.
// 1D grid (nm*ny blocks) with XCD-chunked swizzle: xcd = bid&7 owns m-tiles
// [xcd*nm/8, ...), covering all n-tiles of each m-tile consecutively -> A-panel
// fetched once per XCD into L2 and reused ny times.
// mode 0: store bf16; mode 1: bias+gelu bf16; mode 2: Y += acc+bias (fp32); mode 3: Y = acc+bias (fp32)
__global__ __launch_bounds__(256, 2) void gemm_bt(
    const ushort_t* __restrict__ A, const ushort_t* __restrict__ BT,
    int M, int N, int K,
    const float* __restrict__ bias, int mode,
    ushort_t* __restrict__ C, float* __restrict__ Y) {
    __shared__ ushort_t As[2][128 * 32];
    __shared__ ushort_t Bs[2][128 * 32];
    const int tid = threadIdx.x;
    const int wv = tid >> 6;
    const int lane = tid & 63;
    const int quad = lane >> 4;
    const int l15 = lane & 15;
    const int ny = N >> 7;
    const int nm = gridDim.x / ny;          // 392, divisible by 8
    const int per = nm >> 3;                // m-tiles per XCD
    const int xcd = blockIdx.x & 7;
    const int idx = blockIdx.x >> 3;
    const int mseq = idx / ny;
    const int nt = idx - mseq * ny;
    const long m0 = (long)(xcd * per + mseq) * 128;
    const long n0 = (long)nt * 128;
    const int wm = (wv & 1) * 64;
    const int wn = (wv >> 1) * 64;
    const int r_loc = lane >> 2;
    const int k_loc = (lane & 3) * 8;

    floatx4 acc[4][4] = {};

    const ushort_t* Ab = A + m0 * K;
    const ushort_t* Bb = BT + n0 * K;
    const int slot = wv * 2;
    const int row0 = slot * 16 + r_loc;
    const int nkt = K >> 5;

    // prologue: stage tile 0 into buf 0
#pragma unroll
    for (int q = 0; q < 2; ++q) {
        __builtin_amdgcn_global_load_lds(
            (const __attribute__((address_space(1))) void*)(Ab + (long)(row0 + q * 16) * K + k_loc),
            (__attribute__((address_space(3))) void*)(&As[0][(slot + q) * 512]), 16, 0, 0);
        __builtin_amdgcn_global_load_lds(
            (const __attribute__((address_space(1))) void*)(Bb + (long)(row0 + q * 16) * K + k_loc),
            (__attribute__((address_space(3))) void*)(&Bs[0][(slot + q) * 512]), 16, 0, 0);
    }
    __syncthreads();

    int cur = 0;
    for (int t = 0; t < nkt; ++t) {
        if (t + 1 < nkt) {
            const int kt = (t + 1) << 5;
#pragma unroll
            for (int q = 0; q < 2; ++q) {
                __builtin_amdgcn_global_load_lds(
                    (const __attribute__((address_space(1))) void*)(Ab + (long)(row0 + q * 16) * K + kt + k_loc),
                    (__attribute__((address_space(3))) void*)(&As[cur ^ 1][(slot + q) * 512]), 16, 0, 0);
                __builtin_amdgcn_global_load_lds(
                    (const __attribute__((address_space(1))) void*)(Bb + (long)(row0 + q * 16) * K + kt + k_loc),
                    (__attribute__((address_space(3))) void*)(&Bs[cur ^ 1][(slot + q) * 512]), 16, 0, 0);
            }
        }
        bf16x8 af[4], bfr[4];
#pragma unroll
        for (int i = 0; i < 4; ++i) {
            af[i]  = *(const bf16x8*)(&As[cur][(wm + i * 16 + l15) * 32 + quad * 8]);
            bfr[i] = *(const bf16x8*)(&Bs[cur][(wn + i * 16 + l15) * 32 + quad * 8]);
        }
#pragma unroll
        for (int mi = 0; mi < 4; ++mi)
#pragma unroll
            for (int ni = 0; ni < 4; ++ni)
                acc[mi][ni] = __builtin_amdgcn_mfma_f32_16x16x32_bf16(af[mi], bfr[ni], acc[mi][ni], 0, 0, 0);
        __syncthreads();
        cur ^= 1;
    }

    if (mode == 2) {
#pragma unroll
        for (int mi = 0; mi < 4; ++mi)
#pragma unroll
            for (int ni = 0; ni < 4; ++ni) {
                long col = n0 + wn + ni * 16 + l15;
                float bv = bias[col];
#pragma unroll
                for (int r = 0; r < 4; ++r) {
                    long row = m0 + wm + mi * 16 + quad * 4 + r;
                    Y[row * N + col] += acc[mi][ni][r] + bv;
                }
            }
    } else if (mode == 3) {
#pragma unroll
        for (int mi = 0; mi < 4; ++mi)
#pragma unroll
            for (int ni = 0; ni < 4; ++ni) {
                long col = n0 + wn + ni * 16 + l15;
                float bv = bias[col];
#pragma unroll
                for (int r = 0; r < 4; ++r) {
                    long row = m0 + wm + mi * 16 + quad * 4 + r;
                    Y[row * N + col] = acc[mi][ni][r] + bv;
                }
            }
    } else {
#pragma unroll
        for (int mi = 0; mi < 4; ++mi)
#pragma unroll
            for (int ni = 0; ni < 4; ++ni) {
                long col = n0 + wn + ni * 16 + l15;
                float bv = bias ? bias[col] : 0.f;
#pragma unroll
                for (int r = 0; r < 4; ++r) {
                    long row = m0 + wm + mi * 16 + quad * 4 + r;
                    float v = acc[mi][ni][r] + bv;
                    if (mode == 1) {
                        // gelu(v) = v * sigmoid(2u), u = 0.79788456*(v + 0.044715 v^3)
                        float u = 0.7978845608028654f * (v + 0.044715f * v * v * v);
                        float e = __builtin_amdgcn_exp2f(-2.8853900817779268f * u);
                        v = v * __builtin_amdgcn_rcpf(1.f + e);
                    }
                    C[row * N + col] = f2b(v);
                }
            }
    }
}

// ---------------- MFMA window attention: 1D grid, 8 waves, 2 row-groups/wave.
// Bijective XCD swizzle: 1568 blocks = 8 XCDs x 196; orig = (bid%8)*196 + bid/8
// gives each XCD one head's 196 (win,batch) blocks -> its 256KB bias table slice
// stays L2-resident. Bias table in T[i/4][j][i%4] layout -> one float4 per lane
// covers r=0..3 (16 coalesced loads/rg instead of 64 scalars).
#define PSTR 134            // 67 dwords, odd mod 32
#define VTSTR 266           // 133 dwords, odd mod 32
__global__ __launch_bounds__(512, 4) void attn_mfma(
    const ushort_t* __restrict__ QKV, ushort_t* __restrict__ O,
    const float* __restrict__ Btab, int shifted) {
    __shared__ ushort_t Ks[256 * 32];                 // K rows [tok][dim]   16384 B
    __shared__ ushort_t Vt[32 * VTSTR];               // V^T [dim][tok]      17024 B
    __shared__ ushort_t Pl[8 * 16 * PSTR];            // per-wave P (128 col) 34304 B
    __shared__ int tok_s[256];                        //                      1024 B

    const int tid = threadIdx.x;
    const int wv = tid >> 6;
    const int lane = tid & 63;
    const int quad = lane >> 4;
    const int l15 = lane & 15;
    const int bid = blockIdx.x;
    const int orig = (bid & 7) * 196 + (bid >> 3);
    const int hd = orig / 196;
    const int rem = orig - hd * 196;
    const int b = rem / 98;
    const int wdx = rem - b * 98;
    const int wd = wdx / 49;
    const int wh = (wdx / 7) % 7;
    const int ww = wdx % 7;

    const int cls = shifted ? ((wd << 2) | ((wh == 6) << 1) | (ww == 6)) : 0;
    const float* bt = Btab + ((long)(cls * 8 + hd)) * 65536;

    if (tid < 256) {
        const int t = tid;
        const int di = t >> 6, hi = (t >> 3) & 7, wi = t & 7;
        const int d = wd * 4 + di, h = wh * 8 + hi, w = ww * 8 + wi;
        int d0 = d, h0 = h, w0 = w;
        if (shifted) { d0 = (d + 2) & 7; h0 = (h + 4) % 56; w0 = (w + 4) % 56; }
        const long tok = ((long)((b * 8 + d0) * 56 + h0)) * 56 + w0;
        tok_s[t] = (int)tok;
        const uint4* kp = (const uint4*)(QKV + tok * 768 + 256 + hd * 32);
        const uint4* vp = (const uint4*)(QKV + tok * 768 + 512 + hd * 32);
        uint4* kd = (uint4*)(Ks + t * 32);
#pragma unroll
        for (int p = 0; p < 4; ++p) kd[p] = kp[p];
#pragma unroll
        for (int p = 0; p < 4; ++p) {
            uint4 vvu = vp[p];
            uint_t uu[4] = {vvu.x, vvu.y, vvu.z, vvu.w};
#pragma unroll
            for (int e = 0; e < 4; ++e) {
                int dd = p * 8 + e * 2;
                Vt[dd * VTSTR + t]       = (ushort_t)(uu[e] & 0xffffu);
                Vt[(dd + 1) * VTSTR + t] = (ushort_t)(uu[e] >> 16);
            }
        }
    }
    __syncthreads();

    const float scale = 0.17677669529663687f * 1.4426950408889634f;  // 1/sqrt(32) * log2(e)
    ushort_t* Pw = Pl + wv * 16 * PSTR;

    for (int rg = 0; rg < 2; ++rg) {
        const int rti = wv * 2 + rg;
        bf16x8 aq;
        {
            int tq = tok_s[rti * 16 + l15];
            const uint4* qp = (const uint4*)(QKV + (long)tq * 768 + hd * 32 + quad * 8);
            union { uint4 u; bf16x8 v; } cv; cv.u = *qp; aq = cv.v;
        }
        // bias base: rows rti*16+quad*4.., col l15; layout T[i/4][j][i%4]
        const float* bp = bt + (long)(rti * 4 + quad) * 1024 + l15 * 4;
        floatx4 Sc[16];
        float m4[4] = {-3e38f, -3e38f, -3e38f, -3e38f};
#pragma unroll
        for (int hf = 0; hf < 2; ++hf) {
            floatx4 bb4[8];
#pragma unroll
            for (int n8 = 0; n8 < 8; ++n8)
                bb4[n8] = *(const floatx4*)(bp + (hf * 8 + n8) * 64);   // 16B coalesced
#pragma unroll
            for (int n8 = 0; n8 < 8; ++n8) {
                const int nt = hf * 8 + n8;
                bf16x8 bk = *(const bf16x8*)(Ks + (nt * 16 + l15) * 32 + quad * 8);
                floatx4 z = {};
                Sc[nt] = __builtin_amdgcn_mfma_f32_16x16x32_bf16(aq, bk, z, 0, 0, 0);
            }
#pragma unroll
            for (int n8 = 0; n8 < 8; ++n8) {
                const int nt = hf * 8 + n8;
#pragma unroll
                for (int r = 0; r < 4; ++r) {
                    float s = fmaf(Sc[nt][r], scale, bb4[n8][r]);   // bias+mask, log2 domain
                    Sc[nt][r] = s;
                    m4[r] = fmaxf(m4[r], s);
                }
            }
        }
#pragma unroll
        for (int r = 0; r < 4; ++r) {
            m4[r] = fmaxf(m4[r], __shfl_xor(m4[r], 1));
            m4[r] = fmaxf(m4[r], __shfl_xor(m4[r], 2));
            m4[r] = fmaxf(m4[r], __shfl_xor(m4[r], 4));
            m4[r] = fmaxf(m4[r], __shfl_xor(m4[r], 8));
        }
        float l4[4] = {0.f, 0.f, 0.f, 0.f};
#pragma unroll
        for (int nt = 0; nt < 16; ++nt)
#pragma unroll
            for (int r = 0; r < 4; ++r) {
                float p = __builtin_amdgcn_exp2f(Sc[nt][r] - m4[r]);
                l4[r] += p;
                Sc[nt][r] = p;
            }
#pragma unroll
        for (int r = 0; r < 4; ++r) {
            l4[r] += __shfl_xor(l4[r], 1);
            l4[r] += __shfl_xor(l4[r], 2);
            l4[r] += __shfl_xor(l4[r], 4);
            l4[r] += __shfl_xor(l4[r], 8);
        }
        float inv4[4];
#pragma unroll
        for (int r = 0; r < 4; ++r) inv4[r] = 1.f / l4[r];

        floatx4 oa[2] = {};
#pragma unroll
        for (int hf = 0; hf < 2; ++hf) {
#pragma unroll
            for (int n8 = 0; n8 < 8; ++n8)
#pragma unroll
                for (int r = 0; r < 4; ++r)
                    Pw[(quad * 4 + r) * PSTR + n8 * 16 + l15] = f2b(Sc[hf * 8 + n8][r]);
            __builtin_amdgcn_s_waitcnt(0xC07F);       // lgkmcnt(0)
            __builtin_amdgcn_wave_barrier();
#pragma unroll
            for (int ct = 0; ct < 2; ++ct)
#pragma unroll
                for (int kt = 0; kt < 4; ++kt) {
                    bf16x8 ap = *(const bf16x8*)(Pw + l15 * PSTR + kt * 32 + quad * 8);
                    bf16x8 bv = *(const bf16x8*)(Vt + (ct * 16 + l15) * VTSTR + hf * 128 + kt * 32 + quad * 8);
                    oa[ct] = __builtin_amdgcn_mfma_f32_16x16x32_bf16(ap, bv, oa[ct], 0, 0, 0);
                }
            __builtin_amdgcn_s_waitcnt(0xC07F);
            __builtin_amdgcn_wave_barrier();
        }
#pragma unroll
        for (int ct = 0; ct < 2; ++ct)
#pragma unroll
            for (int r = 0; r < 4; ++r) {
                int i = rti * 16 + quad * 4 + r;
                long tq = tok_s[i];
                O[tq * 256 + hd * 32 + ct * 16 + l15] = f2b(oa[ct][r] * inv4[r]);
            }
    }
}

// ---------------- final permute: y (tok, C) fp32 -> out (B, C, D, Hp, Wp) fp32
__global__ void out_permute(const float* __restrict__ Y, float* __restrict__ Out) {
    __shared__ float tile[64][65];
    const int t0 = blockIdx.x * 64;
    const int c0 = blockIdx.y * 64;
    const int tid = threadIdx.x;
    const int a = tid >> 6;
    const int bx = tid & 63;
#pragma unroll
    for (int s8 = 0; s8 < 16; ++s8) {
        int tt = a + s8 * 4;
        tile[tt][bx] = Y[(long)(t0 + tt) * 256 + c0 + bx];
    }
    __syncthreads();
#pragma unroll
    for (int s8 = 0; s8 < 16; ++s8) {
        int cc = a + s8 * 4;
        int tok = t0 + bx;
        int bb = tok / 25088;
        int rem = tok - bb * 25088;
        Out[((long)(bb * 256 + c0 + cc)) * 25088 + rem] = tile[bx][cc];
    }
}

extern "C" void kernel_launch(void* const* d_in, const int* in_sizes, int n_in,
                              void* d_out, int out_size, void* d_ws, size_t ws_size,
                              hipStream_t stream) {
    (void)in_sizes; (void)n_in; (void)out_size; (void)ws_size;
    const float* x        = (const float*)d_in[0];
    const float* conv_w   = (const float*)d_in[1];
    const float* conv_b   = (const float*)d_in[2];
    const float* ln1_s    = (const float*)d_in[3];
    const float* ln1_b    = (const float*)d_in[4];
    const float* qkv_w    = (const float*)d_in[5];
    const float* out_w    = (const float*)d_in[6];
    const float* out_b    = (const float*)d_in[7];
    const float* bias_tab = (const float*)d_in[8];
    const float* ln2_s    = (const float*)d_in[9];
    const float* ln2_b    = (const float*)d_in[10];
    const float* fc1_w    = (const float*)d_in[11];
    const float* fc1_b    = (const float*)d_in[12];
    const float* fc2_w    = (const float*)d_in[13];
    const float* fc2_b    = (const float*)d_in[14];
    float* out = (float*)d_out;

    char* ws = (char*)d_ws;
    float*    y    = (float*)ws;    ws += (size_t)NTOK * 256 * 4;   // fp32 residual stream
    ushort_t* big  = (ushort_t*)ws; ws += (size_t)NTOK * 1024 * 2;  // qkv/h1/im2row bf16
    ushort_t* xob  = (ushort_t*)ws; ws += (size_t)NTOK * 256 * 2;   // LN out / attn out bf16
    ushort_t* bt_qkv = (ushort_t*)ws; ws += (size_t)4 * 768 * 256 * 2;
    ushort_t* bt_out = (ushort_t*)ws; ws += (size_t)4 * 256 * 256 * 2;
    ushort_t* bt_fc1 = (ushort_t*)ws; ws += (size_t)4 * 1024 * 256 * 2;
    ushort_t* bt_fc2 = (ushort_t*)ws; ws += (size_t)4 * 256 * 1024 * 2;
    ushort_t* cw_bf  = (ushort_t*)ws; ws += (size_t)256 * 64 * 2;
    float*    btab   = (float*)ws;  ws += (size_t)18 * 524288 * 4;  // fused bias+mask tables

    transpose_w<<<dim3((256 * 768 + 255) / 256, 4), 256, 0, stream>>>(qkv_w, bt_qkv, 256, 768);
    transpose_w<<<dim3((256 * 256 + 255) / 256, 4), 256, 0, stream>>>(out_w, bt_out, 256, 256);
    transpose_w<<<dim3((256 * 1024 + 255) / 256, 4), 256, 0, stream>>>(fc1_w, bt_fc1, 256, 1024);
    transpose_w<<<dim3((1024 * 256 + 255) / 256, 4), 256, 0, stream>>>(fc2_w, bt_fc2, 1024, 256);
    gen_btab<<<dim3(2048, 18), 256, 0, stream>>>(bias_tab, btab);

    // conv as GEMM: conv_w (O,I,1,4,4) is already BT[256][64] row-major — cast only
    cast_bf16<<<(256 * 64 + 255) / 256, 256, 0, stream>>>(conv_w, cw_bf, 256 * 64);
    im2row<<<NTOK * 16 / 256, 256, 0, stream>>>(x, big);
    gemm_bt<<<(NTOK / 128) * 2, 256, 0, stream>>>(
        big, cw_bf, NTOK, 256, 64, conv_b, 3, nullptr, y);

    static const int base_slot[4] = {0, 1, 9, 10};
    for (int i = 0; i < 4; ++i) {
        int sh = i & 1;
        ln_kernel<<<NTOK / 4, 256, 0, stream>>>(y, xob, ln1_s + i * 256, ln1_b + i * 256);
        gemm_bt<<<(NTOK / 128) * 6, 256, 0, stream>>>(
            xob, bt_qkv + (size_t)i * 768 * 256, NTOK, 768, 256, nullptr, 0, big, nullptr);
        attn_mfma<<<dim3(NWIN * 8 * 2), 512, 0, stream>>>(
            big, xob, btab + (size_t)base_slot[i] * 524288, sh);
        gemm_bt<<<(NTOK / 128) * 2, 256, 0, stream>>>(
            xob, bt_out + (size_t)i * 256 * 256, NTOK, 256, 256, out_b + i * 256, 2, nullptr, y);
        ln_kernel<<<NTOK / 4, 256, 0, stream>>>(y, xob, ln2_s + i * 256, ln2_b + i * 256);
        gemm_bt<<<(NTOK / 128) * 8, 256, 0, stream>>>(
            xob, bt_fc1 + (size_t)i * 1024 * 256, NTOK, 1024, 256, fc1_b + i * 1024, 1, big, nullptr);
        gemm_bt<<<(NTOK / 128) * 2, 256, 0, stream>>>(
            big, bt_fc2 + (size_t)i * 256 * 1024, NTOK, 256, 1024, fc2_b + i * 256, 2, nullptr, y);
    }

    out_permute<<<dim3(NTOK / 64, 4), 256, 0, stream>>>(y, out);
}